// Round 8
// baseline (136.222 us; speedup 1.0000x reference)
//
#include <hip/hip_runtime.h>
#include <hip/hip_bf16.h>
#include <stdint.h>
#include <math.h>

#define KDIM 2304   // 9 * 256

typedef __attribute__((ext_vector_type(8))) short bf16x8;
typedef __attribute__((ext_vector_type(4))) float f32x4;

__device__ inline unsigned short f2bf(float f) {
  union { float f; unsigned int u; } v; v.f = f;
  unsigned int u = v.u;
  unsigned int r = (u + 0x7FFFu + ((u >> 16) & 1u)) >> 16;
  return (unsigned short)r;
}
__device__ inline float bf2f(unsigned short h) {
  union { unsigned int u; float f; } v; v.u = ((unsigned int)h) << 16;
  return v.f;
}

__device__ inline void gl2lds16(const void* g, void* l) {
  __builtin_amdgcn_global_load_lds((const __attribute__((address_space(1))) void*)g,
                                   (__attribute__((address_space(3))) void*)l,
                                   16, 0, 0);
}

// volatile asm load: compiler cannot sink it, "=v" forces the live range.
#define GLOAD16(dst, ptr) \
  asm volatile("global_load_dwordx4 %0, %1, off" : "=v"(dst) : "v"(ptr))

#define WAITV(N)                                              \
  do {                                                        \
    asm volatile("s_waitcnt vmcnt(" #N ")" ::: "memory");     \
    __builtin_amdgcn_sched_barrier(0);                        \
  } while (0)

// ---------------------------------------------------------------------------
// Kernel 1: fused prep (unchanged, control).
// ---------------------------------------------------------------------------
__global__ __launch_bounds__(256) void k_prep(const float* __restrict__ x,
                                              unsigned short* __restrict__ xTb,
                                              const float* __restrict__ dcn_w,
                                              const float* __restrict__ offset_w,
                                              unsigned short* __restrict__ Wpk,
                                              unsigned short* __restrict__ Wob,
                                              unsigned short* __restrict__ zp) {
  __shared__ float tile[32][65];
  int bx = (int)blockIdx.x;
  int t = threadIdx.x;
  if (bx < 2048) {
    int pt = bx & 127, ct = (bx >> 7) & 3, b = bx >> 9;
    int p0 = pt * 32, c0 = ct * 64;
    const float* xb = x + ((size_t)b << 20);
#pragma unroll
    for (int i = 0; i < 2; ++i) {
      int idx = t + i * 256;
      int c = idx >> 3, pq = idx & 7;
      float4 v = *(const float4*)(xb + ((size_t)(c0 + c) << 12) + p0 + pq * 4);
      tile[pq * 4 + 0][c] = v.x;
      tile[pq * 4 + 1][c] = v.y;
      tile[pq * 4 + 2][c] = v.z;
      tile[pq * 4 + 3][c] = v.w;
    }
    __syncthreads();
    unsigned short* ob = xTb + ((size_t)b << 20);
#pragma unroll
    for (int i = 0; i < 2; ++i) {
      int idx = t + i * 256;
      int p = idx >> 4, cg = idx & 15;
      ushort4 o;
      o.x = f2bf(tile[p][cg * 4 + 0]);
      o.y = f2bf(tile[p][cg * 4 + 1]);
      o.z = f2bf(tile[p][cg * 4 + 2]);
      o.w = f2bf(tile[p][cg * 4 + 3]);
      *(ushort4*)(ob + (((size_t)(p0 + p)) << 8) + c0 + cg * 4) = o;
    }
  } else {
    int gid = (bx - 2048) * 256 + t;
    const int N1 = 72 * 8192;
    const int N2 = 32 * KDIM;
    if (gid < N1) {
      int j = gid & 7;
      int lane = (gid >> 3) & 63;
      int mb = (gid >> 9) & 15;
      int kc = gid >> 13;
      int row = mb * 16 + (lane & 15);
      int gk = kc * 32 + ((lane >> 4) << 3) + j;
      int c = gk & 255, kidx = gk >> 8;
      Wpk[gid] = f2bf(dcn_w[((size_t)(row * 256 + c)) * 9 + kidx]);
    } else if (gid < N1 + N2) {
      int g = gid - N1;
      int ch = g / KDIM, k = g % KDIM;
      int kidx = k >> 8, c = k & 255;
      Wob[g] = (ch < 27) ? f2bf(offset_w[((size_t)(ch * 256 + c)) * 9 + kidx])
                         : (unsigned short)0;
    } else if (gid < N1 + N2 + 128) {
      zp[gid - N1 - N2] = 0;
    }
  }
}

// ---------------------------------------------------------------------------
// Kernel 2: offset conv GEMM + sampling-table epilogue.
//  NEW: BK=64 (36 steps, was 72), tile 64 bhw x 32 offs, 512 thr / 8 waves
//  (mf = wv&3, nf = wv>>2, one 16x16 frag per wave, 2 chunks/step).
//  4-buffer depth-3 pipeline (stage kt+3 after barrier), counted vmcnt.
//  XOR-swizzled A/B LDS: pre-swizzled global source (kpart ^= row&7) +
//  swizzled read -- kills the 128B-row-stride 16-way read conflict (rule 21).
//  Grid 256 with the SAME XCD swizzle as k_fused (SW produced on consumer XCD).
// ---------------------------------------------------------------------------
__global__ __launch_bounds__(512) void k_offs(const unsigned short* __restrict__ xTb,
                                              const unsigned short* __restrict__ Wob,
                                              const unsigned short* __restrict__ zp,
                                              const float* __restrict__ offb,
                                              float* __restrict__ SW) {
  __shared__ unsigned short As[4][64 * 64];   // 32 KB
  __shared__ unsigned short Bsf[4][32 * 64];  // 16 KB
  __shared__ float Os[64][33];                // 8.4 KB
  int t = threadIdx.x;
  int wv = t >> 6, lane = t & 63;
  int bid = (int)blockIdx.x;
  int swz = (bid & 7) * 32 + (bid >> 3);      // 256 = 8 XCDs x 32
  int n0 = swz * 64;

  // A-stage role: row ra (0..63), part ua (0..7); source pre-swizzled.
  int ra = t >> 3, ua = t & 7;
  int kpA = ((ua ^ (ra & 7)) << 3);           // element offset in 64-k step
  int rowA = n0 + ra;
  int b_ = rowA >> 12, hw = rowA & 4095, h = hw >> 6, w = hw & 63;
  // B-stage role (t<256): row rb (0..31), part swizzled likewise.
  int rb = (t >> 3) & 31;
  int kpB = (((t & 7) ^ (rb & 7)) << 3);

  f32x4 acc = {};

  auto stage = [&](int kt) {
    int buf = kt & 3;
    int k0 = kt * 64;
    int kidx = k0 >> 8, c0 = k0 & 255;
    {
      int di = kidx / 3 - 1, dj = kidx % 3 - 1;
      int y = h + di, xx = w + dj;
      const unsigned short* g = (y >= 0 && y < 64 && xx >= 0 && xx < 64)
          ? xTb + (((((size_t)b_) << 12) + (y << 6) + xx) << 8) + c0 + kpA
          : zp;
      gl2lds16(g, (char*)As[buf] + wv * 1024);
    }
    if (t < 256) {
      const unsigned short* gB = Wob + (size_t)rb * KDIM + k0 + kpB;
      gl2lds16(gB, (char*)Bsf[buf] + wv * 1024);
    }
  };

  stage(0); stage(1); stage(2);

  int mf = wv & 3, nf = wv >> 2;
  int arow = mf * 16 + (lane & 15);
  int brow = nf * 16 + (lane & 15);
  int q4 = lane >> 4;
  for (int kt = 0; kt < 36; ++kt) {
    if (kt <= 33) {
      if (wv < 4) asm volatile("s_waitcnt vmcnt(4)" ::: "memory");
      else        asm volatile("s_waitcnt vmcnt(2)" ::: "memory");
    } else if (kt == 34) {
      if (wv < 4) asm volatile("s_waitcnt vmcnt(2)" ::: "memory");
      else        asm volatile("s_waitcnt vmcnt(1)" ::: "memory");
    } else {
      asm volatile("s_waitcnt vmcnt(0)" ::: "memory");
    }
    asm volatile("s_barrier" ::: "memory");
    if (kt + 3 < 36) stage(kt + 3);
    int buf = kt & 3;
#pragma unroll
    for (int cc = 0; cc < 2; ++cc) {
      int kq = (cc << 2) + q4;
      bf16x8 aF = *(const bf16x8*)((const char*)As[buf] +
                                   arow * 128 + (((kq ^ (arow & 7))) << 4));
      bf16x8 bF = *(const bf16x8*)((const char*)Bsf[buf] +
                                   brow * 128 + (((kq ^ (brow & 7))) << 4));
      acc = __builtin_amdgcn_mfma_f32_16x16x32_bf16(aF, bF, acc, 0, 0, 0);
    }
  }

  // epilogue: fragment -> Os -> sampling table
  int quad = lane >> 4, cl = lane & 15;
#pragma unroll
  for (int r = 0; r < 4; ++r)
    Os[mf * 16 + quad * 4 + r][nf * 16 + cl] = acc[r];
  __syncthreads();

  for (int item = t; item < 576; item += 512) {
    int bl = item & 63, k = item >> 6;
    int bhw = n0 + bl;
    int h_ = (bhw >> 6) & 63, w_ = bhw & 63;
    float dy = Os[bl][2 * k]     + offb[2 * k];
    float dx = Os[bl][2 * k + 1] + offb[2 * k + 1];
    float mv = Os[bl][18 + k]    + offb[18 + k];
    float mask = 1.0f / (1.0f + expf(-mv));

    float py = (float)(h_ - 1 + k / 3) + dy;
    float px = (float)(w_ - 1 + k % 3) + dx;
    float y0f = floorf(py), x0f = floorf(px);
    float wy = py - y0f, wx = px - x0f;
    int y0 = (int)y0f, x0 = (int)x0f;
    int y1 = y0 + 1, x1 = x0 + 1;

    float vy0 = (y0 >= 0 && y0 < 64) ? 1.f : 0.f;
    float vy1 = (y1 >= 0 && y1 < 64) ? 1.f : 0.f;
    float vx0 = (x0 >= 0 && x0 < 64) ? 1.f : 0.f;
    float vx1 = (x1 >= 0 && x1 < 64) ? 1.f : 0.f;
    int y0c = min(max(y0, 0), 63), y1c = min(max(y1, 0), 63);
    int x0c = min(max(x0, 0), 63), x1c = min(max(x1, 0), 63);

    float4 wv4;
    wv4.x = (1.f - wy) * (1.f - wx) * vy0 * vx0 * mask;
    wv4.y = (1.f - wy) * wx * vy0 * vx1 * mask;
    wv4.z = wy * (1.f - wx) * vy1 * vx0 * mask;
    wv4.w = wy * wx * vy1 * vx1 * mask;
    uint4 ov;
    ov.x = (unsigned)(((y0c << 6) + x0c) << 8);
    ov.y = (unsigned)(((y0c << 6) + x1c) << 8);
    ov.z = (unsigned)(((y1c << 6) + x0c) << 8);
    ov.w = (unsigned)(((y1c << 6) + x1c) << 8);

    float* p = SW + (size_t)(k * 16384 + bhw) * 8;
    *(float4*)p = wv4;
    *(uint4*)(p + 4) = ov;
  }
}

// ---------------------------------------------------------------------------
// Kernel 3: fused sample + main GEMM, BK=128 (18 phases), asm-pinned pipeline.
//  Per phase (one kidx, one corner set): thread role r=t>>3 (row), u=t&7
//  (16-channel slice): 8 q-loads (4 corners x 32B), blend 16 elems, 2 LDS
//  writes; 4 chunks x 8 MFMA with per-chunk aF reload (aF(p+1)[c] issued
//  right after MFMA consumes aF(p)[c]).
//  vmcnt ledger (volatile-asm order: ..., q(p), [chunks: aF(p)], q(p+1),
//  [chunks: aF(p+1)], ...):
//   blend-wait:  newer than q(p) = aF(p)16          -> vmcnt(16)
//   chunk c:     newer than aF(p)[c] = 4(3-c)+8+4c  -> vmcnt(20)  (steady)
//   tail p=17:   4(3-c)                             -> 12/8/4/0
//  LDS: Bs rows 136 shorts (272B = 17x16B: aligned b128, <=2-way banks).
// ---------------------------------------------------------------------------
#define FCHUNK(P, CC, BUF, ISSUE, W)                                           \
  do {                                                                         \
    WAITV(W);                                                                  \
    bf16x8 bF0_ = *(const bf16x8*)(                                            \
        &Bs[BUF][(wn * 32 + (lane & 15)) * 136 + (CC) * 32 + (lane >> 4) * 8]);\
    bf16x8 bF1_ = *(const bf16x8*)(                                            \
        &Bs[BUF][(wn * 32 + 16 + (lane & 15)) * 136 + (CC) * 32 +              \
                 (lane >> 4) * 8]);                                            \
    _Pragma("unroll")                                                          \
    for (int i_ = 0; i_ < 4; ++i_) {                                           \
      acc[i_][0] = __builtin_amdgcn_mfma_f32_16x16x32_bf16(                    \
          aF[(CC) * 4 + i_], bF0_, acc[i_][0], 0, 0, 0);                       \
      acc[i_][1] = __builtin_amdgcn_mfma_f32_16x16x32_bf16(                    \
          aF[(CC) * 4 + i_], bF1_, acc[i_][1], 0, 0, 0);                       \
    }                                                                          \
    if (ISSUE) {                                                               \
      _Pragma("unroll")                                                        \
      for (int i_ = 0; i_ < 4; ++i_)                                           \
        GLOAD16(aF[(CC) * 4 + i_],                                             \
                wpBase + ((size_t)((((P) + 1) * 4 + (CC)) * 16 + i_)) * 512);  \
    }                                                                          \
  } while (0)

#define FPHASE(P, BUF, ISSUE, W0, W1, W2, W3)                                  \
  do {                                                                         \
    if ((((P) & 1) == 0) && (P) < 16) {                                        \
      int g_ = ((P) >> 1) + 1;                                                 \
      wv4n = *(const float4*)(SWL + (size_t)(g_ * 128 + r * 2) * 4);           \
      ovn  = *(const uint4*)(SWL + (size_t)(g_ * 128 + r * 2 + 1) * 4);        \
    }                                                                          \
    WAITV(16);                                                                 \
    float s_[16];                                                              \
    _Pragma("unroll")                                                          \
    for (int j_ = 0; j_ < 8; ++j_) {                                           \
      s_[j_] = wv4.x * bf2f((unsigned short)q[0][j_]) +                        \
               wv4.y * bf2f((unsigned short)q[1][j_]) +                        \
               wv4.z * bf2f((unsigned short)q[2][j_]) +                        \
               wv4.w * bf2f((unsigned short)q[3][j_]);                         \
      s_[8 + j_] = wv4.x * bf2f((unsigned short)q[4][j_]) +                    \
                   wv4.y * bf2f((unsigned short)q[5][j_]) +                    \
                   wv4.z * bf2f((unsigned short)q[6][j_]) +                    \
                   wv4.w * bf2f((unsigned short)q[7][j_]);                     \
    }                                                                          \
    union { __hip_bfloat162 h2[4]; bf16x8 v; } pka_, pkb_;                     \
    pka_.h2[0] = __float22bfloat162_rn(make_float2(s_[0], s_[1]));             \
    pka_.h2[1] = __float22bfloat162_rn(make_float2(s_[2], s_[3]));             \
    pka_.h2[2] = __float22bfloat162_rn(make_float2(s_[4], s_[5]));             \
    pka_.h2[3] = __float22bfloat162_rn(make_float2(s_[6], s_[7]));             \
    pkb_.h2[0] = __float22bfloat162_rn(make_float2(s_[8], s_[9]));             \
    pkb_.h2[1] = __float22bfloat162_rn(make_float2(s_[10], s_[11]));           \
    pkb_.h2[2] = __float22bfloat162_rn(make_float2(s_[12], s_[13]));           \
    pkb_.h2[3] = __float22bfloat162_rn(make_float2(s_[14], s_[15]));           \
    *(bf16x8*)(&Bs[BUF][bsw])     = pka_.v;                                    \
    *(bf16x8*)(&Bs[BUF][bsw + 8]) = pkb_.v;                                    \
    if (ISSUE) {                                                               \
      uint4 o_ = (((P) & 1) ? ovn : ov);                                       \
      unsigned cb_ = (unsigned)((((((P) + 1)) & 1) << 7) + u * 16);            \
      GLOAD16(q[0], xb + o_.x + cb_);                                          \
      GLOAD16(q[1], xb + o_.y + cb_);                                          \
      GLOAD16(q[2], xb + o_.z + cb_);                                          \
      GLOAD16(q[3], xb + o_.w + cb_);                                          \
      GLOAD16(q[4], xb + o_.x + cb_ + 8);                                      \
      GLOAD16(q[5], xb + o_.y + cb_ + 8);                                      \
      GLOAD16(q[6], xb + o_.z + cb_ + 8);                                      \
      GLOAD16(q[7], xb + o_.w + cb_ + 8);                                      \
    }                                                                          \
    asm volatile("s_waitcnt lgkmcnt(0)\n\ts_barrier" ::: "memory");            \
    __builtin_amdgcn_sched_barrier(0);                                         \
    FCHUNK(P, 0, BUF, ISSUE, W0);                                              \
    FCHUNK(P, 1, BUF, ISSUE, W1);                                              \
    FCHUNK(P, 2, BUF, ISSUE, W2);                                              \
    FCHUNK(P, 3, BUF, ISSUE, W3);                                              \
  } while (0)

__global__ __launch_bounds__(512, 2) void k_fused(const unsigned short* __restrict__ Wpk,
                                                  const unsigned short* __restrict__ xTb,
                                                  const float* __restrict__ SW,
                                                  float* __restrict__ out) {
  __shared__ __align__(16) unsigned short Bs[2][64 * 136];  // 34.8 KB
  __shared__ __align__(16) float SWL[1152 * 4];             // 18.4 KB
  int t = threadIdx.x;
  int wv = t >> 6, lane = t & 63;
  int wm = wv & 3, wn = wv >> 2;
  int bid = (int)blockIdx.x;
  int swz = (bid & 7) * 32 + (bid >> 3);
  int n0 = swz * 64;
  int b  = n0 >> 12;
  const unsigned short* xb = xTb + ((size_t)b << 20);

  // sampling role: row r (0..63), channel slice u (0..7) of 16 channels
  int r = t >> 3;
  int u = t & 7;
  int bsw = r * 136 + u * 16;

  const unsigned short* wpBase = Wpk + ((size_t)(wm * 4 * 64 + lane)) * 8;

  f32x4 acc[4][2] = {};

  // --- stage SW table (64 rows x 9 groups x 32B = 18KB) into LDS ---
  {
#pragma unroll
    for (int i = 0; i < 3; ++i) {
      int hs = t + i * 512;
      if (hs < 1152) {
        int grp = hs >> 7, row = (hs >> 1) & 63, hh = hs & 1;
        const float* src = SW + ((size_t)(grp * 16384 + n0 + row)) * 8 + hh * 4;
        char* dstbase = (char*)SWL + ((size_t)((t & ~63) + i * 512)) * 16;
        gl2lds16(src, dstbase);
      }
    }
  }
  asm volatile("s_waitcnt vmcnt(0)" ::: "memory");
  __builtin_amdgcn_s_barrier();

  float4 wv4, wv4n; uint4 ov, ovn;
  wv4 = *(const float4*)(SWL + (size_t)(r * 2) * 4);
  ov  = *(const uint4*)(SWL + (size_t)(r * 2 + 1) * 4);
  wv4n = wv4; ovn = ov;

  bf16x8 q[8];
  bf16x8 aF[16];

  // prologue: q(0) then aF(0) (canonical volatile order)
  {
    unsigned cb = (unsigned)(u * 16);
    GLOAD16(q[0], xb + ov.x + cb);
    GLOAD16(q[1], xb + ov.y + cb);
    GLOAD16(q[2], xb + ov.z + cb);
    GLOAD16(q[3], xb + ov.w + cb);
    GLOAD16(q[4], xb + ov.x + cb + 8);
    GLOAD16(q[5], xb + ov.y + cb + 8);
    GLOAD16(q[6], xb + ov.z + cb + 8);
    GLOAD16(q[7], xb + ov.w + cb + 8);
#pragma unroll
    for (int cc = 0; cc < 4; ++cc)
#pragma unroll
      for (int i = 0; i < 4; ++i)
        GLOAD16(aF[cc * 4 + i], wpBase + ((size_t)(cc * 16 + i)) * 512);
  }

  for (int p = 0; p < 16; p += 2) {
    FPHASE(p,     0, 1, 20, 20, 20, 20);
    FPHASE(p + 1, 1, 1, 20, 20, 20, 20);
    wv4 = wv4n; ov = ovn;   // rotate after odd phase (group loaded at even)
  }
  FPHASE(16, 0, 1, 20, 20, 20, 20);
  FPHASE(17, 1, 0, 12, 8, 4, 0);

  // epilogue
  int quad = lane >> 4, cl = lane & 15;
  float* ob = out + (((size_t)b) << 20);
#pragma unroll
  for (int i = 0; i < 4; ++i) {
    int mbase = wm * 64 + i * 16 + quad * 4;
#pragma unroll
    for (int j = 0; j < 2; ++j) {
      int hw = (n0 & 4095) + wn * 32 + j * 16 + cl;
      float* op = ob + hw;
#pragma unroll
      for (int rr = 0; rr < 4; ++rr)
        op[((size_t)(mbase + rr)) << 12] = acc[i][j][rr];
    }
  }
}

// ---------------------------------------------------------------------------
extern "C" void kernel_launch(void* const* d_in, const int* in_sizes, int n_in,
                              void* d_out, int out_size, void* d_ws, size_t ws_size,
                              hipStream_t stream) {
  const float* x        = (const float*)d_in[0];
  const float* offset_w = (const float*)d_in[1];
  const float* offset_b = (const float*)d_in[2];
  const float* dcn_w    = (const float*)d_in[3];
  float* out = (float*)d_out;

  char* ws = (char*)d_ws;
  size_t off = 0;
  auto carve = [&](size_t bytes) -> void* {
    void* p = ws + off;
    off += (bytes + 255) & ~(size_t)255;
    return p;
  };
  unsigned short* xTb = (unsigned short*)carve(4ull * 64 * 64 * 256 * 2);   // 8 MB
  unsigned short* Wpk = (unsigned short*)carve(72ull * 8192 * 2);           // 1.125 MB
  unsigned short* Wob = (unsigned short*)carve(32ull * KDIM * 2);           // 144 KB
  unsigned short* zp  = (unsigned short*)carve(256);                        // zero page
  float*          SW  = (float*)carve(9ull * 16384 * 8 * 4);                // 4.5 MB
  (void)ws_size; (void)in_sizes; (void)n_in; (void)out_size;

  const int WPREP_BLOCKS = (72 * 8192 + 32 * KDIM + 128 + 255) / 256;
  k_prep<<<dim3(2048 + WPREP_BLOCKS), 256, 0, stream>>>(
      x, xTb, dcn_w, offset_w, Wpk, Wob, zp);
  k_offs<<<dim3(256), 512, 0, stream>>>(xTb, Wob, zp, offset_b, SW);
  k_fused<<<dim3(256), 512, 0, stream>>>(Wpk, xTb, SW, out);
}